// Round 6
// baseline (102.379 us; speedup 1.0000x reference)
//
#include <hip/hip_runtime.h>

// PosEncoding: coords [1, N, 3] f32 -> out [1, N, 63] f32
// out[n][0:3]             = coords[n][0:3]
// out[n][3 + i*6 + j*2]   = sin(coords[n][j] * 2^i * pi)   i=0..9, j=0..2
// out[n][3 + i*6 + j*2+1] = cos(coords[n][j] * 2^i * pi)
//
// Angle in REVOLUTIONS: c * 2^i * pi rad == c * 2^(i-1) rev (exact doubling).
// fract() reduces to [0,1); v_sin_f32/v_cos_f32 take revolutions.
//
// Structure identical to round 5 (1-wave blocks, LDS coord staging + LDS
// output tile, coalesced f32x4 copy-out). ONE change: phase-2 stores are
// nontemporal (A/B vs round 5's plain stores). If neutral -> roofline.

typedef float f32x4 __attribute__((ext_vector_type(4)));

#define BLOCK_THREADS  64
#define WAVE_PTS       64
#define OUT_PER_POINT  63
#define WAVE_FLOATS    (WAVE_PTS * OUT_PER_POINT)   // 4032
#define WAVE_V4        (WAVE_FLOATS / 4)            // 1008
#define CSTAGE_V4      (WAVE_PTS * 3 / 4)           // 48 (768 B)

__global__ __launch_bounds__(BLOCK_THREADS) void posenc_kernel(
    const float* __restrict__ coords,
    f32x4* __restrict__ out4,
    int n_points)
{
    __shared__ f32x4 tile4[WAVE_V4];
    __shared__ f32x4 cstage4[CSTAGE_V4];
    float* tile   = (float*)tile4;
    float* cstage = (float*)cstage4;

    const int lane = (int)threadIdx.x;
    const long long pbase = (long long)blockIdx.x * WAVE_PTS;

    // ---- phase 0: cooperative aligned coord load (768 B per wave) ----
    {
        const long long in_v4 = (long long)n_points * 3 / 4;  // total f32x4 in coords
        const long long cb    = (long long)blockIdx.x * CSTAGE_V4;
        if (lane < CSTAGE_V4 && cb + lane < in_v4) {
            cstage4[lane] = ((const f32x4*)coords)[cb + lane];
        }
    }
    __syncthreads();   // 1-wave block: near-free, guarantees LDS ordering

    // ---- phase 1: compute this thread's point into the LDS tile ----
    if (pbase + lane < n_points) {
        const float c0 = cstage[lane * 3 + 0];
        const float c1 = cstage[lane * 3 + 1];
        const float c2 = cstage[lane * 3 + 2];

        float* o = &tile[lane * OUT_PER_POINT];
        o[0] = c0; o[1] = c1; o[2] = c2;

        // revolutions for freq i: c * 2^(i-1)
        float r0 = c0 * 0.5f, r1 = c1 * 0.5f, r2 = c2 * 0.5f;

        int k = 3;
        #pragma unroll
        for (int i = 0; i < 10; ++i) {
            const float f0 = r0 - floorf(r0);
            const float f1 = r1 - floorf(r1);
            const float f2 = r2 - floorf(r2);
            o[k + 0] = __builtin_amdgcn_sinf(f0);
            o[k + 1] = __builtin_amdgcn_cosf(f0);
            o[k + 2] = __builtin_amdgcn_sinf(f1);
            o[k + 3] = __builtin_amdgcn_cosf(f1);
            o[k + 4] = __builtin_amdgcn_sinf(f2);
            o[k + 5] = __builtin_amdgcn_cosf(f2);
            k += 6;
            r0 *= 2.0f; r1 *= 2.0f; r2 *= 2.0f;  // exact doubling
        }
    }
    __syncthreads();

    // ---- phase 2: coalesced nontemporal f32x4 copy-out (16128 B) ----
    const long long gbase = (long long)blockIdx.x * WAVE_V4;
    const long long gmax  = (long long)n_points * OUT_PER_POINT / 4;

    if (gbase + WAVE_V4 <= gmax) {           // full block: unguarded fast path
        #pragma unroll
        for (int it = 0; it < WAVE_V4 / 64; ++it)          // 15 full iters
            __builtin_nontemporal_store(tile4[it * 64 + lane],
                                        &out4[gbase + it * 64 + lane]);
        if (lane < (WAVE_V4 & 63))                          // 48-lane tail
            __builtin_nontemporal_store(tile4[(WAVE_V4 / 64) * 64 + lane],
                                        &out4[gbase + (WAVE_V4 / 64) * 64 + lane]);
    } else {                                  // partial last block
        for (int v = lane; v < WAVE_V4; v += 64)
            if (gbase + v < gmax)
                __builtin_nontemporal_store(tile4[v], &out4[gbase + v]);
    }
}

extern "C" void kernel_launch(void* const* d_in, const int* in_sizes, int n_in,
                              void* d_out, int out_size, void* d_ws, size_t ws_size,
                              hipStream_t stream) {
    const float* coords = (const float*)d_in[0];
    f32x4* out4 = (f32x4*)d_out;

    const int n_points = in_sizes[0] / 3;                        // 2,097,152
    const int grid = (n_points + WAVE_PTS - 1) / WAVE_PTS;       // 32768

    posenc_kernel<<<grid, BLOCK_THREADS, 0, stream>>>(coords, out4, n_points);
}

// Round 7
// 98.676 us; speedup vs baseline: 1.0375x; 1.0375x over previous
//
#include <hip/hip_runtime.h>

// PosEncoding: coords [1, N, 3] f32 -> out [1, N, 63] f32
// out[n][0:3]             = coords[n][0:3]
// out[n][3 + i*6 + j*2]   = sin(coords[n][j] * 2^i * pi)   i=0..9, j=0..2
// out[n][3 + i*6 + j*2+1] = cos(coords[n][j] * 2^i * pi)
//
// Angle in REVOLUTIONS: c * 2^i * pi rad == c * 2^(i-1) rev (exact doubling).
// fract() reduces to [0,1); v_sin_f32/v_cos_f32 take revolutions.
//
// FINAL (round-5 structure, plain stores — nt A/B'd at −2.7%, reverted):
//   1-wave (64-thread) blocks, each an independent pipeline:
//   phase 0: cooperative aligned f32x4 load of the wave's 768 B coord panel
//            into LDS (each 64B line fetched exactly once),
//   phase 1: per-thread compute of one point's 63 outputs into the LDS tile,
//   phase 2: coalesced f32x4 copy-out of the wave's contiguous 16128 B range.
// 99.7 us = 5.78 TB/s = 92% of measured mixed-stream ceiling (m13 6.29 TB/s).

typedef float f32x4 __attribute__((ext_vector_type(4)));

#define BLOCK_THREADS  64
#define WAVE_PTS       64
#define OUT_PER_POINT  63
#define WAVE_FLOATS    (WAVE_PTS * OUT_PER_POINT)   // 4032
#define WAVE_V4        (WAVE_FLOATS / 4)            // 1008
#define CSTAGE_V4      (WAVE_PTS * 3 / 4)           // 48 (768 B)

__global__ __launch_bounds__(BLOCK_THREADS) void posenc_kernel(
    const float* __restrict__ coords,
    f32x4* __restrict__ out4,
    int n_points)
{
    __shared__ f32x4 tile4[WAVE_V4];
    __shared__ f32x4 cstage4[CSTAGE_V4];
    float* tile   = (float*)tile4;
    float* cstage = (float*)cstage4;

    const int lane = (int)threadIdx.x;
    const long long pbase = (long long)blockIdx.x * WAVE_PTS;

    // ---- phase 0: cooperative aligned coord load (768 B per wave) ----
    {
        const long long in_v4 = (long long)n_points * 3 / 4;  // total f32x4 in coords
        const long long cb    = (long long)blockIdx.x * CSTAGE_V4;
        if (lane < CSTAGE_V4 && cb + lane < in_v4) {
            cstage4[lane] = ((const f32x4*)coords)[cb + lane];
        }
    }
    __syncthreads();   // 1-wave block: near-free, guarantees LDS ordering

    // ---- phase 1: compute this thread's point into the LDS tile ----
    if (pbase + lane < n_points) {
        const float c0 = cstage[lane * 3 + 0];
        const float c1 = cstage[lane * 3 + 1];
        const float c2 = cstage[lane * 3 + 2];

        float* o = &tile[lane * OUT_PER_POINT];
        o[0] = c0; o[1] = c1; o[2] = c2;

        // revolutions for freq i: c * 2^(i-1)
        float r0 = c0 * 0.5f, r1 = c1 * 0.5f, r2 = c2 * 0.5f;

        int k = 3;
        #pragma unroll
        for (int i = 0; i < 10; ++i) {
            const float f0 = r0 - floorf(r0);
            const float f1 = r1 - floorf(r1);
            const float f2 = r2 - floorf(r2);
            o[k + 0] = __builtin_amdgcn_sinf(f0);
            o[k + 1] = __builtin_amdgcn_cosf(f0);
            o[k + 2] = __builtin_amdgcn_sinf(f1);
            o[k + 3] = __builtin_amdgcn_cosf(f1);
            o[k + 4] = __builtin_amdgcn_sinf(f2);
            o[k + 5] = __builtin_amdgcn_cosf(f2);
            k += 6;
            r0 *= 2.0f; r1 *= 2.0f; r2 *= 2.0f;  // exact doubling
        }
    }
    __syncthreads();

    // ---- phase 2: coalesced f32x4 copy-out (contiguous 16128 B) ----
    const long long gbase = (long long)blockIdx.x * WAVE_V4;
    const long long gmax  = (long long)n_points * OUT_PER_POINT / 4;

    if (gbase + WAVE_V4 <= gmax) {           // full block: unguarded fast path
        #pragma unroll
        for (int it = 0; it < WAVE_V4 / 64; ++it)          // 15 full iters
            out4[gbase + it * 64 + lane] = tile4[it * 64 + lane];
        if (lane < (WAVE_V4 & 63))                          // 48-lane tail
            out4[gbase + (WAVE_V4 / 64) * 64 + lane] = tile4[(WAVE_V4 / 64) * 64 + lane];
    } else {                                  // partial last block
        for (int v = lane; v < WAVE_V4; v += 64)
            if (gbase + v < gmax) out4[gbase + v] = tile4[v];
    }
}

extern "C" void kernel_launch(void* const* d_in, const int* in_sizes, int n_in,
                              void* d_out, int out_size, void* d_ws, size_t ws_size,
                              hipStream_t stream) {
    const float* coords = (const float*)d_in[0];
    f32x4* out4 = (f32x4*)d_out;

    const int n_points = in_sizes[0] / 3;                        // 2,097,152
    const int grid = (n_points + WAVE_PTS - 1) / WAVE_PTS;       // 32768

    posenc_kernel<<<grid, BLOCK_THREADS, 0, stream>>>(coords, out4, n_points);
}